// Round 3
// baseline (221.827 us; speedup 1.0000x reference)
//
#include <hip/hip_runtime.h>

// DHSMoEDetector: N=16384 tokens, D=768, H=768, C=2, E=20
#define N_D 768
#define N_H 768
#define N_C 2
#define N_E 20
#define MT 128
#define NT 128
#define BK 32
#define KT (N_D / BK)
#define MAX_TILES 160
#define NCOL (N_H / NT)  // 6 column blocks
#define ROWB (N_D * 2)   // row stride in bytes (bf16)
#define W1BLKS (N_E * (N_D / 64) * (N_H / 64))  // 2880 w1-convert blocks

typedef __attribute__((ext_vector_type(8))) short short8;
typedef __attribute__((ext_vector_type(4))) float f32x4;

__device__ __forceinline__ unsigned short f2bf(float f) {
  unsigned u = __builtin_bit_cast(unsigned, f);
  u += 0x7FFFu + ((u >> 16) & 1u);
  return (unsigned short)(u >> 16);
}

#define GLD_LDS16(gp, lp)                                                        \
  __builtin_amdgcn_global_load_lds(                                              \
      (const __attribute__((address_space(1))) void*)(gp),                       \
      (__attribute__((address_space(3))) void*)(lp), 16, 0, 0)

// ---------------- fused W1 transpose/convert + expert histogram ------------
// W1 (E,D,H) fp32 -> W1t (E,H,D) bf16 row-major (16B stores), plus the
// token histogram rides along in the last `hb` blocks (its 64KB of cidx
// traffic hides under W1's 71MB stream).

__global__ __launch_bounds__(256) void k_prep(const float* __restrict__ W1,
                                              unsigned short* __restrict__ W1t,
                                              const int* __restrict__ cidx,
                                              int* __restrict__ counts, int n,
                                              int hb) {
  __shared__ float tile[64][65];
  __shared__ int lc[N_E];
  if ((int)blockIdx.x < W1BLKS) {
    int bid = blockIdx.x;
    int e = bid / 144;
    int rem = bid - e * 144;
    int h0 = (rem % 12) * 64, d0 = (rem / 12) * 64;
    const float* src = W1 + (size_t)e * N_D * N_H;
    unsigned short* dst = W1t + (size_t)e * N_H * N_D;
    int tx = threadIdx.x & 15, ty = threadIdx.x >> 4;
#pragma unroll
    for (int s = 0; s < 4; ++s) {
      int d = s * 16 + ty;
      float4 v = *(const float4*)&src[(size_t)(d0 + d) * N_H + h0 + tx * 4];
      tile[d][tx * 4 + 0] = v.x;
      tile[d][tx * 4 + 1] = v.y;
      tile[d][tx * 4 + 2] = v.z;
      tile[d][tx * 4 + 3] = v.w;
    }
    __syncthreads();
    int px = threadIdx.x & 7, py = threadIdx.x >> 3;
#pragma unroll
    for (int s = 0; s < 2; ++s) {
      int h = s * 32 + py;
      short8 v;
#pragma unroll
      for (int j = 0; j < 8; ++j)
        v[j] = (short)f2bf(tile[px * 8 + j][h]);
      *(short8*)&dst[(size_t)(h0 + h) * N_D + d0 + px * 8] = v;
    }
  } else {
    int b = blockIdx.x - W1BLKS;
    if (threadIdx.x < N_E) lc[threadIdx.x] = 0;
    __syncthreads();
    for (int i = b * 256 + threadIdx.x; i < n; i += hb * 256) {
      int e = cidx[i];
      e = e < 0 ? 0 : (e >= N_E ? N_E - 1 : e);
      atomicAdd(&lc[e], 1);
    }
    __syncthreads();
    if (threadIdx.x < N_E) atomicAdd(&counts[threadIdx.x], lc[threadIdx.x]);
  }
}

// ---------------- parallel scan (one wave) ----------------

__global__ void k_scan(const int* __restrict__ counts, int* __restrict__ offsets,
                       int* __restrict__ cursor, int* __restrict__ tiles,
                       int* __restrict__ numTiles) {
  int lane = threadIdx.x;
  int c = (lane < N_E) ? counts[lane] : 0;
  int nt = (c + MT - 1) / MT;
  int cs = c, ts = nt;
#pragma unroll
  for (int s = 1; s < 32; s <<= 1) {
    int t1 = __shfl_up(cs, s, 64);
    int t2 = __shfl_up(ts, s, 64);
    if (lane >= s) {
      cs += t1;
      ts += t2;
    }
  }
  int coff = cs - c;
  int tbase = ts - nt;
  if (lane < N_E) {
    offsets[lane] = coff;
    cursor[lane] = coff;
    for (int m = 0; m < nt; ++m) {
      int t = tbase + m;
      if (t < MAX_TILES) tiles[t] = (lane << 8) | m;
    }
  }
  if (lane == N_E - 1) *numTiles = ts > MAX_TILES ? MAX_TILES : ts;
}

// ---------------- fused scatter + gather (fp32 -> bf16, sorted order) ------

#define SG_TOK 64

__global__ __launch_bounds__(256) void k_scatter_gather(
    const int* __restrict__ cidx, int* __restrict__ cursor,
    int* __restrict__ sorted, const float* __restrict__ emb,
    unsigned short* __restrict__ Xg, int n) {
  __shared__ int lc[N_E];
  __shared__ int lbase[N_E];
  __shared__ int pos_s[SG_TOK];
  const int tid = threadIdx.x;
  const int nb = (n + SG_TOK - 1) / SG_TOK;
  if ((int)blockIdx.x >= nb) {
    // pad block: zero rows [n, n+MT) so tail tiles read zeros
    ushort4 z = {0, 0, 0, 0};
    ushort4* dst = (ushort4*)(Xg + (size_t)n * N_D);
    for (int k = tid; k < MT * N_D / 4; k += 256) dst[k] = z;
    return;
  }
  const int base_tok = blockIdx.x * SG_TOK;
  if (tid < N_E) lc[tid] = 0;
  __syncthreads();
  const int i = base_tok + tid;
  int e = 0, p = 0;
  if (tid < SG_TOK && i < n) {
    e = cidx[i];
    e = e < 0 ? 0 : (e >= N_E ? N_E - 1 : e);
    p = atomicAdd(&lc[e], 1);
  }
  __syncthreads();
  if (tid < N_E) lbase[tid] = atomicAdd(&cursor[tid], lc[tid]);
  __syncthreads();
  if (tid < SG_TOK) {
    if (i < n) {
      int pos = lbase[e] + p;
      sorted[pos] = i;
      pos_s[tid] = pos;
    } else {
      pos_s[tid] = -1;
    }
  }
  __syncthreads();
  const int wid = tid >> 6, lane = tid & 63;
  int nrows = n - base_tok;
  if (nrows > SG_TOK) nrows = SG_TOK;
  for (int rr = wid; rr < nrows; rr += 4) {
    const float4* s = (const float4*)(emb + (size_t)(base_tok + rr) * N_D);
    ushort4* d = (ushort4*)(Xg + (size_t)pos_s[rr] * N_D);
#pragma unroll
    for (int p2 = 0; p2 < 3; ++p2) {
      float4 v = s[lane + p2 * 64];
      ushort4 o;
      o.x = f2bf(v.x);
      o.y = f2bf(v.y);
      o.z = f2bf(v.z);
      o.w = f2bf(v.w);
      d[lane + p2 * 64] = o;
    }
  }
}

// ---------------- fused grouped GEMM1 + relu + layer2 ----------------------
// Round-1 proven structure (depth-2 LDS pipeline, chunk-major conflict-free
// staging, XCD chunk swizzle) at 4 blocks/CU: __launch_bounds__(256,4) fits
// 60 VGPR + 64 AGPR = 124 <= 128 unified regs, 4x32KB = 128KB LDS. All ~840
// active blocks co-resident -> 16 waves/CU to hide per-step load latency.

__global__ __launch_bounds__(256, 4) void k_gemm(
    const unsigned short* __restrict__ Xg, const unsigned short* __restrict__ W1t,
    const float* __restrict__ b1, const float* __restrict__ W2,
    const float* __restrict__ b2, const int* __restrict__ sorted,
    const int* __restrict__ counts, const int* __restrict__ offsets,
    const int* __restrict__ tiles, const int* __restrict__ numTiles,
    float* __restrict__ out) {
  const int nactive = *numTiles * NCOL;
  const int lin = (int)blockIdx.y * NCOL + (int)blockIdx.x;
  if (lin >= nactive) return;
  const int q = nactive >> 3, r = nactive & 7;
  const int c = lin & 7, ii = lin >> 3;
  const int wgid = (c < r ? c * (q + 1) : r * (q + 1) + (c - r) * q) + ii;
  const int tileIdx = wgid / NCOL;
  const int n0 = (wgid - tileIdx * NCOL) * NT;

  const int tv = tiles[tileIdx];
  const int e = tv >> 8;
  const int m0 = (tv & 255) * MT;
  const int off = offsets[e];
  const int cnt_rel = counts[e] - m0;

  __shared__ unsigned short lA[2][MT * BK];  // 2 x 8KB, chunk-major groups
  __shared__ unsigned short lB[2][NT * BK];

  const int tid = threadIdx.x;
  const int wid = tid >> 6, lane = tid & 63;
  const int wm = (wid >> 1) * 64, wn = (wid & 1) * 64;
  const int quad = lane >> 4, lm = lane & 15;

  const int R0 = wid * 32 + lm;
  const char* agp = (const char*)Xg + (size_t)(off + m0 + R0) * ROWB + quad * 16;
  const char* bgp = (const char*)W1t + (size_t)e * N_H * ROWB +
                    (size_t)(n0 + R0) * ROWB + quad * 16;
  unsigned short* lap[2] = {&lA[0][(wid * 32) * BK], &lA[1][(wid * 32) * BK]};
  unsigned short* lbp[2] = {&lB[0][(wid * 32) * BK], &lB[1][(wid * 32) * BK]};

#define ISSUE_BATCH(kk, b)                                                       \
  do {                                                                           \
    const char* a_ = agp + (kk)*64;                                              \
    const char* b_ = bgp + (kk)*64;                                              \
    GLD_LDS16(a_, lap[b]);                                                       \
    GLD_LDS16(a_ + 16 * ROWB, lap[b] + 16 * BK);                                 \
    GLD_LDS16(b_, lbp[b]);                                                       \
    GLD_LDS16(b_ + 16 * ROWB, lbp[b] + 16 * BK);                                 \
  } while (0)

  f32x4 acc[4][4] = {};

  ISSUE_BATCH(0, 0);
  ISSUE_BATCH(1, 1);

  const int fa = quad * 128 + lm * 8;

  for (int kt = 0; kt < KT; ++kt) {
    const int cur = kt & 1;
    asm volatile("s_waitcnt vmcnt(4)\n\ts_barrier" ::: "memory");
    short8 af[4], bfr[4];
    for (int i = 0; i < 4; ++i)
      af[i] = *(const short8*)&lA[cur][((wm >> 4) + i) * 512 + fa];
    for (int j = 0; j < 4; ++j)
      bfr[j] = *(const short8*)&lB[cur][((wn >> 4) + j) * 512 + fa];
    asm volatile("s_waitcnt lgkmcnt(0)\n\ts_barrier" ::: "memory");
    int kk = kt + 2;
    if (kk >= KT) kk -= KT;  // dummy re-load keeps vmcnt bookkeeping uniform
    ISSUE_BATCH(kk, cur);
    for (int i = 0; i < 4; ++i)
      for (int j = 0; j < 4; ++j)
        acc[i][j] =
            __builtin_amdgcn_mfma_f32_16x16x32_bf16(af[i], bfr[j], acc[i][j], 0, 0, 0);
  }

  // ---- fused epilogue: h = relu(acc + b1), y-partial = h * W2[e] ----
  float y0[4][4], y1[4][4];
  for (int i = 0; i < 4; ++i)
    for (int r2 = 0; r2 < 4; ++r2) y0[i][r2] = y1[i][r2] = 0.f;

  for (int j = 0; j < 4; ++j) {
    int col = n0 + wn + j * 16 + lm;
    float bias = b1[e * N_H + col];
    float2 w2 = *(const float2*)&W2[((size_t)e * N_H + col) * N_C];
    for (int i = 0; i < 4; ++i) {
      f32x4 a = acc[i][j];
      for (int r2 = 0; r2 < 4; ++r2) {
        float h = a[r2] + bias;
        h = h > 0.f ? h : 0.f;
        y0[i][r2] += h * w2.x;
        y1[i][r2] += h * w2.y;
      }
    }
  }
  for (int s = 1; s < 16; s <<= 1) {
    for (int i = 0; i < 4; ++i)
      for (int r2 = 0; r2 < 4; ++r2) {
        y0[i][r2] += __shfl_xor(y0[i][r2], s, 64);
        y1[i][r2] += __shfl_xor(y1[i][r2], s, 64);
      }
  }
  if (lm == 0) {
    const bool add_bias = (n0 == 0) && (wn == 0);
    float bb0 = add_bias ? b2[e * N_C + 0] : 0.f;
    float bb1 = add_bias ? b2[e * N_C + 1] : 0.f;
    for (int i = 0; i < 4; ++i) {
      for (int r2 = 0; r2 < 4; ++r2) {
        int mrel = wm + i * 16 + quad * 4 + r2;
        if (mrel < cnt_rel) {
          int token = sorted[off + m0 + mrel];
          atomicAdd(&out[(size_t)token * N_C + 0], y0[i][r2] + bb0);
          atomicAdd(&out[(size_t)token * N_C + 1], y1[i][r2] + bb1);
        }
      }
    }
  }
}

// ---------------- launch ----------------

extern "C" void kernel_launch(void* const* d_in, const int* in_sizes, int n_in,
                              void* d_out, int out_size, void* d_ws, size_t ws_size,
                              hipStream_t stream) {
  const float* emb = (const float*)d_in[0];
  const int* cidx = (const int*)d_in[1];
  const float* W1 = (const float*)d_in[2];
  const float* b1 = (const float*)d_in[3];
  const float* W2 = (const float*)d_in[4];
  const float* b2 = (const float*)d_in[5];
  float* out = (float*)d_out;
  const int n = in_sizes[1];

  char* ws = (char*)d_ws;
  int* counts = (int*)ws;
  int* offsets = (int*)(ws + 128);
  int* cursor = (int*)(ws + 256);
  int* numTiles = (int*)(ws + 384);
  int* tiles = (int*)(ws + 512);
  int* sorted = (int*)(ws + 2048);
  size_t sorted_bytes = ((size_t)n * 4 + 255) & ~(size_t)255;
  unsigned short* Xg = (unsigned short*)(ws + 2048 + sorted_bytes);
  int pcap = n + MT;  // zero-padded tail rows
  unsigned short* W1t = Xg + (size_t)pcap * N_D;

  hipMemsetAsync(d_ws, 0, 2048, stream);
  hipMemsetAsync(d_out, 0, (size_t)out_size * sizeof(float), stream);
  int hb = (n + 255) / 256;
  k_prep<<<W1BLKS + hb, 256, 0, stream>>>(W1, W1t, cidx, counts, n, hb);
  k_scan<<<1, 64, 0, stream>>>(counts, offsets, cursor, tiles, numTiles);
  int nb64 = (n + SG_TOK - 1) / SG_TOK;
  k_scatter_gather<<<nb64 + 1, 256, 0, stream>>>(cidx, cursor, sorted, emb, Xg, n);
  k_gemm<<<dim3(NCOL, MAX_TILES), 256, 0, stream>>>(
      Xg, W1t, b1, W2, b2, sorted, counts, offsets, tiles, numTiles, out);
}

// Round 4
// 207.337 us; speedup vs baseline: 1.0699x; 1.0699x over previous
//
#include <hip/hip_runtime.h>

// DHSMoEDetector: N=16384 tokens, D=768, H=768, C=2, E=20
#define N_D 768
#define N_H 768
#define N_C 2
#define N_E 20
#define MT 128
#define NT 128
#define BK 32
#define KT (N_D / BK)
#define MAX_TILES 160
#define NCOL (N_H / NT)  // 6 column blocks
#define ROWB (N_D * 2)   // row stride in bytes (bf16)
#define W1BLKS (N_E * (N_D / 64) * (N_H / 64))  // 2880 w1-convert blocks
#define HB 64                                   // histogram blocks

typedef __attribute__((ext_vector_type(8))) short short8;
typedef __attribute__((ext_vector_type(4))) float f32x4;

__device__ __forceinline__ unsigned short f2bf(float f) {
  unsigned u = __builtin_bit_cast(unsigned, f);
  u += 0x7FFFu + ((u >> 16) & 1u);
  return (unsigned short)(u >> 16);
}

#define GLD_LDS16(gp, lp)                                                        \
  __builtin_amdgcn_global_load_lds(                                              \
      (const __attribute__((address_space(1))) void*)(gp),                       \
      (__attribute__((address_space(3))) void*)(lp), 16, 0, 0)

// ---------------- fused: W1 transpose/convert + partial hist + out-zero ----
// First W1BLKS blocks: W1 (E,D,H) fp32 -> W1t (E,H,D) bf16.
// Last HB blocks: per-block expert histogram written with PLAIN stores to
// partials[b][e] (no global zero-init needed), and zero `out` (replaces the
// 128KB memset dispatch).

__global__ __launch_bounds__(256) void k_prep(const float* __restrict__ W1,
                                              unsigned short* __restrict__ W1t,
                                              const int* __restrict__ cidx,
                                              int* __restrict__ partials,
                                              float* __restrict__ out, int n) {
  __shared__ float tile[64][65];
  __shared__ int lc[N_E];
  if ((int)blockIdx.x < W1BLKS) {
    int bid = blockIdx.x;
    int e = bid / 144;
    int rem = bid - e * 144;
    int h0 = (rem % 12) * 64, d0 = (rem / 12) * 64;
    const float* src = W1 + (size_t)e * N_D * N_H;
    unsigned short* dst = W1t + (size_t)e * N_H * N_D;
    int tx = threadIdx.x & 15, ty = threadIdx.x >> 4;
#pragma unroll
    for (int s = 0; s < 4; ++s) {
      int d = s * 16 + ty;
      float4 v = *(const float4*)&src[(size_t)(d0 + d) * N_H + h0 + tx * 4];
      tile[d][tx * 4 + 0] = v.x;
      tile[d][tx * 4 + 1] = v.y;
      tile[d][tx * 4 + 2] = v.z;
      tile[d][tx * 4 + 3] = v.w;
    }
    __syncthreads();
    int px = threadIdx.x & 7, py = threadIdx.x >> 3;
#pragma unroll
    for (int s = 0; s < 2; ++s) {
      int h = s * 32 + py;
      short8 v;
#pragma unroll
      for (int j = 0; j < 8; ++j)
        v[j] = (short)f2bf(tile[px * 8 + j][h]);
      *(short8*)&dst[(size_t)(h0 + h) * N_D + d0 + px * 8] = v;
    }
  } else {
    int b = blockIdx.x - W1BLKS;
    int tid = threadIdx.x;
    if (tid < N_E) lc[tid] = 0;
    __syncthreads();
    for (int i = b * 256 + tid; i < n; i += HB * 256) {
      int e = cidx[i];
      e = e < 0 ? 0 : (e >= N_E ? N_E - 1 : e);
      atomicAdd(&lc[e], 1);
    }
    __syncthreads();
    if (tid < N_E) partials[b * 32 + tid] = lc[tid];
    // zero out[] (N_C * n floats) across the HB blocks
    for (int idx = b * 256 + tid; idx < N_C * n; idx += HB * 256) out[idx] = 0.f;
  }
}

// ---------------- parallel scan (one wave): sum partials, scan, tiles ------

__global__ void k_scan(const int* __restrict__ partials, int* __restrict__ counts,
                       int* __restrict__ offsets, int* __restrict__ cursor,
                       int* __restrict__ tiles, int* __restrict__ numTiles) {
  int lane = threadIdx.x;
  int c = 0;
  if (lane < N_E) {
#pragma unroll
    for (int b = 0; b < HB; ++b) c += partials[b * 32 + lane];
  }
  int nt = (c + MT - 1) / MT;
  int cs = c, ts = nt;
#pragma unroll
  for (int s = 1; s < 32; s <<= 1) {
    int t1 = __shfl_up(cs, s, 64);
    int t2 = __shfl_up(ts, s, 64);
    if (lane >= s) {
      cs += t1;
      ts += t2;
    }
  }
  int coff = cs - c;
  int tbase = ts - nt;
  if (lane < N_E) {
    counts[lane] = c;
    offsets[lane] = coff;
    cursor[lane] = coff;
    for (int m = 0; m < nt; ++m) {
      int t = tbase + m;
      if (t < MAX_TILES) tiles[t] = (lane << 8) | m;
    }
  }
  if (lane == N_E - 1) *numTiles = ts > MAX_TILES ? MAX_TILES : ts;
}

// ---------------- fused scatter + gather (fp32 -> bf16, sorted order) ------
// 512 threads (8 waves) per 64 tokens: position phase on threads 0..63,
// then 8 waves copy 8 rows each (3x float4 per lane per row). Extra waves
// double the latency-hiding for the dependent load->cvt->store chains.

#define SG_TOK 64

__global__ __launch_bounds__(512) void k_scatter_gather(
    const int* __restrict__ cidx, int* __restrict__ cursor,
    int* __restrict__ sorted, const float* __restrict__ emb,
    unsigned short* __restrict__ Xg, int n) {
  __shared__ int lc[N_E];
  __shared__ int lbase[N_E];
  __shared__ int pos_s[SG_TOK];
  const int tid = threadIdx.x;
  const int nb = (n + SG_TOK - 1) / SG_TOK;
  if ((int)blockIdx.x >= nb) {
    // pad block: zero rows [n, n+MT) so tail tiles read zeros
    ushort4 z = {0, 0, 0, 0};
    ushort4* dst = (ushort4*)(Xg + (size_t)n * N_D);
    for (int k = tid; k < MT * N_D / 4; k += 512) dst[k] = z;
    return;
  }
  const int base_tok = blockIdx.x * SG_TOK;
  if (tid < N_E) lc[tid] = 0;
  __syncthreads();
  const int i = base_tok + tid;
  int e = 0, p = 0;
  if (tid < SG_TOK && i < n) {
    e = cidx[i];
    e = e < 0 ? 0 : (e >= N_E ? N_E - 1 : e);
    p = atomicAdd(&lc[e], 1);
  }
  __syncthreads();
  if (tid < N_E) lbase[tid] = atomicAdd(&cursor[tid], lc[tid]);
  __syncthreads();
  if (tid < SG_TOK) {
    if (i < n) {
      int pos = lbase[e] + p;
      sorted[pos] = i;
      pos_s[tid] = pos;
    } else {
      pos_s[tid] = -1;
    }
  }
  __syncthreads();
  const int wid = tid >> 6, lane = tid & 63;
  int nrows = n - base_tok;
  if (nrows > SG_TOK) nrows = SG_TOK;
  for (int rr = wid; rr < nrows; rr += 8) {
    const float4* s = (const float4*)(emb + (size_t)(base_tok + rr) * N_D);
    ushort4* d = (ushort4*)(Xg + (size_t)pos_s[rr] * N_D);
#pragma unroll
    for (int p2 = 0; p2 < 3; ++p2) {
      float4 v = s[lane + p2 * 64];
      ushort4 o;
      o.x = f2bf(v.x);
      o.y = f2bf(v.y);
      o.z = f2bf(v.z);
      o.w = f2bf(v.w);
      d[lane + p2 * 64] = o;
    }
  }
}

// ---------------- fused grouped GEMM1 + relu + layer2 ----------------------
// Round-1 proven structure, VERBATIM: depth-2 LDS pipeline, chunk-major
// conflict-free staging, XCD chunk swizzle, __launch_bounds__(256,2).

__global__ __launch_bounds__(256, 2) void k_gemm(
    const unsigned short* __restrict__ Xg, const unsigned short* __restrict__ W1t,
    const float* __restrict__ b1, const float* __restrict__ W2,
    const float* __restrict__ b2, const int* __restrict__ sorted,
    const int* __restrict__ counts, const int* __restrict__ offsets,
    const int* __restrict__ tiles, const int* __restrict__ numTiles,
    float* __restrict__ out) {
  const int nactive = *numTiles * NCOL;
  const int lin = (int)blockIdx.y * NCOL + (int)blockIdx.x;
  if (lin >= nactive) return;
  const int q = nactive >> 3, r = nactive & 7;
  const int c = lin & 7, ii = lin >> 3;
  const int wgid = (c < r ? c * (q + 1) : r * (q + 1) + (c - r) * q) + ii;
  const int tileIdx = wgid / NCOL;
  const int n0 = (wgid - tileIdx * NCOL) * NT;

  const int tv = tiles[tileIdx];
  const int e = tv >> 8;
  const int m0 = (tv & 255) * MT;
  const int off = offsets[e];
  const int cnt_rel = counts[e] - m0;

  __shared__ unsigned short lA[2][MT * BK];  // 2 x 8KB, chunk-major groups
  __shared__ unsigned short lB[2][NT * BK];

  const int tid = threadIdx.x;
  const int wid = tid >> 6, lane = tid & 63;
  const int wm = (wid >> 1) * 64, wn = (wid & 1) * 64;
  const int quad = lane >> 4, lm = lane & 15;

  const int R0 = wid * 32 + lm;
  const char* agp = (const char*)Xg + (size_t)(off + m0 + R0) * ROWB + quad * 16;
  const char* bgp = (const char*)W1t + (size_t)e * N_H * ROWB +
                    (size_t)(n0 + R0) * ROWB + quad * 16;
  unsigned short* lap[2] = {&lA[0][(wid * 32) * BK], &lA[1][(wid * 32) * BK]};
  unsigned short* lbp[2] = {&lB[0][(wid * 32) * BK], &lB[1][(wid * 32) * BK]};

#define ISSUE_BATCH(kk, b)                                                       \
  do {                                                                           \
    const char* a_ = agp + (kk)*64;                                              \
    const char* b_ = bgp + (kk)*64;                                              \
    GLD_LDS16(a_, lap[b]);                                                       \
    GLD_LDS16(a_ + 16 * ROWB, lap[b] + 16 * BK);                                 \
    GLD_LDS16(b_, lbp[b]);                                                       \
    GLD_LDS16(b_ + 16 * ROWB, lbp[b] + 16 * BK);                                 \
  } while (0)

  f32x4 acc[4][4] = {};

  ISSUE_BATCH(0, 0);
  ISSUE_BATCH(1, 1);

  const int fa = quad * 128 + lm * 8;

  for (int kt = 0; kt < KT; ++kt) {
    const int cur = kt & 1;
    asm volatile("s_waitcnt vmcnt(4)\n\ts_barrier" ::: "memory");
    short8 af[4], bfr[4];
    for (int i = 0; i < 4; ++i)
      af[i] = *(const short8*)&lA[cur][((wm >> 4) + i) * 512 + fa];
    for (int j = 0; j < 4; ++j)
      bfr[j] = *(const short8*)&lB[cur][((wn >> 4) + j) * 512 + fa];
    asm volatile("s_waitcnt lgkmcnt(0)\n\ts_barrier" ::: "memory");
    int kk = kt + 2;
    if (kk >= KT) kk -= KT;  // dummy re-load keeps vmcnt bookkeeping uniform
    ISSUE_BATCH(kk, cur);
    for (int i = 0; i < 4; ++i)
      for (int j = 0; j < 4; ++j)
        acc[i][j] =
            __builtin_amdgcn_mfma_f32_16x16x32_bf16(af[i], bfr[j], acc[i][j], 0, 0, 0);
  }

  // ---- fused epilogue: h = relu(acc + b1), y-partial = h * W2[e] ----
  float y0[4][4], y1[4][4];
  for (int i = 0; i < 4; ++i)
    for (int r2 = 0; r2 < 4; ++r2) y0[i][r2] = y1[i][r2] = 0.f;

  for (int j = 0; j < 4; ++j) {
    int col = n0 + wn + j * 16 + lm;
    float bias = b1[e * N_H + col];
    float2 w2 = *(const float2*)&W2[((size_t)e * N_H + col) * N_C];
    for (int i = 0; i < 4; ++i) {
      f32x4 a = acc[i][j];
      for (int r2 = 0; r2 < 4; ++r2) {
        float h = a[r2] + bias;
        h = h > 0.f ? h : 0.f;
        y0[i][r2] += h * w2.x;
        y1[i][r2] += h * w2.y;
      }
    }
  }
  for (int s = 1; s < 16; s <<= 1) {
    for (int i = 0; i < 4; ++i)
      for (int r2 = 0; r2 < 4; ++r2) {
        y0[i][r2] += __shfl_xor(y0[i][r2], s, 64);
        y1[i][r2] += __shfl_xor(y1[i][r2], s, 64);
      }
  }
  if (lm == 0) {
    const bool add_bias = (n0 == 0) && (wn == 0);
    float bb0 = add_bias ? b2[e * N_C + 0] : 0.f;
    float bb1 = add_bias ? b2[e * N_C + 1] : 0.f;
    for (int i = 0; i < 4; ++i) {
      for (int r2 = 0; r2 < 4; ++r2) {
        int mrel = wm + i * 16 + quad * 4 + r2;
        if (mrel < cnt_rel) {
          int token = sorted[off + m0 + mrel];
          atomicAdd(&out[(size_t)token * N_C + 0], y0[i][r2] + bb0);
          atomicAdd(&out[(size_t)token * N_C + 1], y1[i][r2] + bb1);
        }
      }
    }
  }
}

// ---------------- launch ----------------

extern "C" void kernel_launch(void* const* d_in, const int* in_sizes, int n_in,
                              void* d_out, int out_size, void* d_ws, size_t ws_size,
                              hipStream_t stream) {
  const float* emb = (const float*)d_in[0];
  const int* cidx = (const int*)d_in[1];
  const float* W1 = (const float*)d_in[2];
  const float* b1 = (const float*)d_in[3];
  const float* W2 = (const float*)d_in[4];
  const float* b2 = (const float*)d_in[5];
  float* out = (float*)d_out;
  const int n = in_sizes[1];

  char* ws = (char*)d_ws;
  int* counts = (int*)ws;
  int* offsets = (int*)(ws + 128);
  int* cursor = (int*)(ws + 256);
  int* numTiles = (int*)(ws + 384);
  int* tiles = (int*)(ws + 512);
  int* partials = (int*)(ws + 2048);              // HB x 32 ints = 8KB
  int* sorted = (int*)(ws + 2048 + HB * 32 * 4);  // ws + 10240
  size_t sorted_bytes = ((size_t)n * 4 + 255) & ~(size_t)255;
  unsigned short* Xg = (unsigned short*)(ws + 2048 + HB * 32 * 4 + sorted_bytes);
  int pcap = n + MT;  // zero-padded tail rows
  unsigned short* W1t = Xg + (size_t)pcap * N_D;

  // 4 dispatches, no memsets: partial hists use plain stores, out zeroed in
  // k_prep, tiles/offsets/counts/cursor fully rewritten each iteration.
  k_prep<<<W1BLKS + HB, 256, 0, stream>>>(W1, W1t, cidx, partials, out, n);
  k_scan<<<1, 64, 0, stream>>>(partials, counts, offsets, cursor, tiles, numTiles);
  int nb64 = (n + SG_TOK - 1) / SG_TOK;
  k_scatter_gather<<<nb64 + 1, 512, 0, stream>>>(cidx, cursor, sorted, emb, Xg, n);
  k_gemm<<<dim3(NCOL, MAX_TILES), 256, 0, stream>>>(
      Xg, W1t, b1, W2, b2, sorted, counts, offsets, tiles, numTiles, out);
}

// Round 5
// 205.889 us; speedup vs baseline: 1.0774x; 1.0070x over previous
//
#include <hip/hip_runtime.h>

// DHSMoEDetector: N=16384 tokens, D=768, H=768, C=2, E=20
#define N_D 768
#define N_H 768
#define N_C 2
#define N_E 20
#define MT 128
#define NT 128
#define BK 32
#define KT (N_D / BK)
#define MAX_TILES 160
#define NCOL (N_H / NT)  // 6 column blocks
#define ROWB (N_D * 2)   // row stride in bytes (bf16)
#define W1BLKS (N_E * (N_D / 64) * (N_H / 64))  // 2880 w1-convert blocks
#define SG_TOK 64

typedef __attribute__((ext_vector_type(8))) short short8;
typedef __attribute__((ext_vector_type(4))) float f32x4;

__device__ __forceinline__ unsigned short f2bf(float f) {
  unsigned u = __builtin_bit_cast(unsigned, f);
  u += 0x7FFFu + ((u >> 16) & 1u);
  return (unsigned short)(u >> 16);
}

#define GLD_LDS16(gp, lp)                                                        \
  __builtin_amdgcn_global_load_lds(                                              \
      (const __attribute__((address_space(1))) void*)(gp),                       \
      (__attribute__((address_space(3))) void*)(lp), 16, 0, 0)

// ---------------- front: single-block histogram + scan + tile list ---------
// Replaces (64 hist blocks -> scan) with one ~8us block: per-wave LDS
// sub-histograms (4x less atomic contention), int4-vectorized cidx reads,
// then a wave-level prefix scan over the 20 experts.

__global__ __launch_bounds__(256) void k_front(const int* __restrict__ cidx,
                                               int* __restrict__ counts,
                                               int* __restrict__ offsets,
                                               int* __restrict__ cursor,
                                               int* __restrict__ tiles,
                                               int* __restrict__ numTiles, int n) {
  __shared__ int lc[4][N_E];
  __shared__ int tot[N_E];
  const int tid = threadIdx.x;
  const int w = tid >> 6;
  for (int k = tid; k < 4 * N_E; k += 256) ((int*)lc)[k] = 0;
  __syncthreads();
  const int4* c4 = (const int4*)cidx;
  const int nv = n >> 2;
  for (int i = tid; i < nv; i += 256) {
    int4 v = c4[i];
    int e0 = v.x < 0 ? 0 : (v.x >= N_E ? N_E - 1 : v.x);
    int e1 = v.y < 0 ? 0 : (v.y >= N_E ? N_E - 1 : v.y);
    int e2 = v.z < 0 ? 0 : (v.z >= N_E ? N_E - 1 : v.z);
    int e3 = v.w < 0 ? 0 : (v.w >= N_E ? N_E - 1 : v.w);
    atomicAdd(&lc[w][e0], 1);
    atomicAdd(&lc[w][e1], 1);
    atomicAdd(&lc[w][e2], 1);
    atomicAdd(&lc[w][e3], 1);
  }
  for (int i = (nv << 2) + tid; i < n; i += 256) {
    int e = cidx[i];
    e = e < 0 ? 0 : (e >= N_E ? N_E - 1 : e);
    atomicAdd(&lc[w][e], 1);
  }
  __syncthreads();
  if (tid < N_E) tot[tid] = lc[0][tid] + lc[1][tid] + lc[2][tid] + lc[3][tid];
  __syncthreads();
  if (tid < 64) {
    int lane = tid;
    int c = (lane < N_E) ? tot[lane] : 0;
    int nt = (c + MT - 1) / MT;
    int cs = c, ts = nt;
#pragma unroll
    for (int s = 1; s < 32; s <<= 1) {
      int t1 = __shfl_up(cs, s, 64);
      int t2 = __shfl_up(ts, s, 64);
      if (lane >= s) {
        cs += t1;
        ts += t2;
      }
    }
    int coff = cs - c;
    int tbase = ts - nt;
    if (lane < N_E) {
      counts[lane] = c;
      offsets[lane] = coff;
      cursor[lane] = coff;
      for (int m = 0; m < nt; ++m) {
        int t = tbase + m;
        if (t < MAX_TILES) tiles[t] = (lane << 8) | m;
      }
    }
    if (lane == N_E - 1) *numTiles = ts > MAX_TILES ? MAX_TILES : ts;
  }
}

// ---------------- mid: scatter+gather AND W1-convert in ONE dispatch -------
// sg blocks (first nbsg): claim sorted positions via cursor atomics, copy+cvt
// token rows emb fp32 -> Xg bf16. Pad block zeroes Xg tail rows AND out[].
// w1 blocks (remaining W1BLKS): W1 (E,D,H) fp32 -> W1t (E,H,D) bf16 with a
// bijective XCD chunk remap (2880 = 8*360) so the 12 h-blocks sharing a
// 192KB d-row-stripe are co-resident on ONE XCD's L2 -> W1 fetched once.
// Sharing one grid lets W1's streaming BW hide the gather's latency chains.

__global__ __launch_bounds__(256) void k_mid(
    const int* __restrict__ cidx, int* __restrict__ cursor,
    int* __restrict__ sorted, const float* __restrict__ emb,
    unsigned short* __restrict__ Xg, const float* __restrict__ W1,
    unsigned short* __restrict__ W1t, float* __restrict__ out, int n, int nbsg) {
  __shared__ float tile[64][65];
  __shared__ int lc[N_E];
  __shared__ int lbase[N_E];
  __shared__ int pos_s[SG_TOK];
  const int tid = threadIdx.x;

  if ((int)blockIdx.x >= nbsg) {
    // ---- W1 convert/transpose with XCD chunk remap ----
    int w1i = blockIdx.x - nbsg;
    int xcd = w1i & 7, ii = w1i >> 3;
    int wgid = xcd * (W1BLKS / 8) + ii;
    int e = wgid / 144;
    int rem = wgid - e * 144;
    int h0 = (rem % 12) * 64, d0 = (rem / 12) * 64;
    const float* src = W1 + (size_t)e * N_D * N_H;
    unsigned short* dst = W1t + (size_t)e * N_H * N_D;
    int tx = tid & 15, ty = tid >> 4;
#pragma unroll
    for (int s = 0; s < 4; ++s) {
      int d = s * 16 + ty;
      float4 v = *(const float4*)&src[(size_t)(d0 + d) * N_H + h0 + tx * 4];
      tile[d][tx * 4 + 0] = v.x;
      tile[d][tx * 4 + 1] = v.y;
      tile[d][tx * 4 + 2] = v.z;
      tile[d][tx * 4 + 3] = v.w;
    }
    __syncthreads();
    int px = tid & 7, py = tid >> 3;
#pragma unroll
    for (int s = 0; s < 2; ++s) {
      int h = s * 32 + py;
      short8 v;
#pragma unroll
      for (int j = 0; j < 8; ++j)
        v[j] = (short)f2bf(tile[px * 8 + j][h]);
      *(short8*)&dst[(size_t)(h0 + h) * N_D + d0 + px * 8] = v;
    }
    return;
  }

  const int nb = (n + SG_TOK - 1) / SG_TOK;
  if ((int)blockIdx.x >= nb) {
    // pad block: zero Xg rows [n, n+MT) so tail tiles read zeros; zero out[]
    ushort4 z = {0, 0, 0, 0};
    ushort4* dst = (ushort4*)(Xg + (size_t)n * N_D);
    for (int k = tid; k < MT * N_D / 4; k += 256) dst[k] = z;
    float4 zf = {0.f, 0.f, 0.f, 0.f};
    float4* of = (float4*)out;
    for (int k = tid; k < N_C * n / 4; k += 256) of[k] = zf;
    return;
  }
  const int base_tok = blockIdx.x * SG_TOK;
  if (tid < N_E) lc[tid] = 0;
  __syncthreads();
  const int i = base_tok + tid;
  int e = 0, p = 0;
  if (tid < SG_TOK && i < n) {
    e = cidx[i];
    e = e < 0 ? 0 : (e >= N_E ? N_E - 1 : e);
    p = atomicAdd(&lc[e], 1);
  }
  __syncthreads();
  if (tid < N_E) lbase[tid] = atomicAdd(&cursor[tid], lc[tid]);
  __syncthreads();
  if (tid < SG_TOK) {
    if (i < n) {
      int pos = lbase[e] + p;
      sorted[pos] = i;
      pos_s[tid] = pos;
    } else {
      pos_s[tid] = -1;
    }
  }
  __syncthreads();
  const int wid = tid >> 6, lane = tid & 63;
  int nrows = n - base_tok;
  if (nrows > SG_TOK) nrows = SG_TOK;
  for (int rr = wid; rr < nrows; rr += 4) {
    const float4* s = (const float4*)(emb + (size_t)(base_tok + rr) * N_D);
    ushort4* d = (ushort4*)(Xg + (size_t)pos_s[rr] * N_D);
#pragma unroll
    for (int p2 = 0; p2 < 3; ++p2) {
      float4 v = s[lane + p2 * 64];
      ushort4 o;
      o.x = f2bf(v.x);
      o.y = f2bf(v.y);
      o.z = f2bf(v.z);
      o.w = f2bf(v.w);
      d[lane + p2 * 64] = o;
    }
  }
}

// ---------------- fused grouped GEMM1 + relu + layer2 ----------------------
// Round-1 proven structure, VERBATIM (74.5us, 60 VGPR): depth-2 LDS pipeline,
// chunk-major conflict-free staging, XCD chunk swizzle, launch_bounds(256,2).

__global__ __launch_bounds__(256, 2) void k_gemm(
    const unsigned short* __restrict__ Xg, const unsigned short* __restrict__ W1t,
    const float* __restrict__ b1, const float* __restrict__ W2,
    const float* __restrict__ b2, const int* __restrict__ sorted,
    const int* __restrict__ counts, const int* __restrict__ offsets,
    const int* __restrict__ tiles, const int* __restrict__ numTiles,
    float* __restrict__ out) {
  const int nactive = *numTiles * NCOL;
  const int lin = (int)blockIdx.y * NCOL + (int)blockIdx.x;
  if (lin >= nactive) return;
  const int q = nactive >> 3, r = nactive & 7;
  const int c = lin & 7, ii = lin >> 3;
  const int wgid = (c < r ? c * (q + 1) : r * (q + 1) + (c - r) * q) + ii;
  const int tileIdx = wgid / NCOL;
  const int n0 = (wgid - tileIdx * NCOL) * NT;

  const int tv = tiles[tileIdx];
  const int e = tv >> 8;
  const int m0 = (tv & 255) * MT;
  const int off = offsets[e];
  const int cnt_rel = counts[e] - m0;

  __shared__ unsigned short lA[2][MT * BK];  // 2 x 8KB, chunk-major groups
  __shared__ unsigned short lB[2][NT * BK];

  const int tid = threadIdx.x;
  const int wid = tid >> 6, lane = tid & 63;
  const int wm = (wid >> 1) * 64, wn = (wid & 1) * 64;
  const int quad = lane >> 4, lm = lane & 15;

  const int R0 = wid * 32 + lm;
  const char* agp = (const char*)Xg + (size_t)(off + m0 + R0) * ROWB + quad * 16;
  const char* bgp = (const char*)W1t + (size_t)e * N_H * ROWB +
                    (size_t)(n0 + R0) * ROWB + quad * 16;
  unsigned short* lap[2] = {&lA[0][(wid * 32) * BK], &lA[1][(wid * 32) * BK]};
  unsigned short* lbp[2] = {&lB[0][(wid * 32) * BK], &lB[1][(wid * 32) * BK]};

#define ISSUE_BATCH(kk, b)                                                       \
  do {                                                                           \
    const char* a_ = agp + (kk)*64;                                              \
    const char* b_ = bgp + (kk)*64;                                              \
    GLD_LDS16(a_, lap[b]);                                                       \
    GLD_LDS16(a_ + 16 * ROWB, lap[b] + 16 * BK);                                 \
    GLD_LDS16(b_, lbp[b]);                                                       \
    GLD_LDS16(b_ + 16 * ROWB, lbp[b] + 16 * BK);                                 \
  } while (0)

  f32x4 acc[4][4] = {};

  ISSUE_BATCH(0, 0);
  ISSUE_BATCH(1, 1);

  const int fa = quad * 128 + lm * 8;

  for (int kt = 0; kt < KT; ++kt) {
    const int cur = kt & 1;
    asm volatile("s_waitcnt vmcnt(4)\n\ts_barrier" ::: "memory");
    short8 af[4], bfr[4];
    for (int i = 0; i < 4; ++i)
      af[i] = *(const short8*)&lA[cur][((wm >> 4) + i) * 512 + fa];
    for (int j = 0; j < 4; ++j)
      bfr[j] = *(const short8*)&lB[cur][((wn >> 4) + j) * 512 + fa];
    asm volatile("s_waitcnt lgkmcnt(0)\n\ts_barrier" ::: "memory");
    int kk = kt + 2;
    if (kk >= KT) kk -= KT;  // dummy re-load keeps vmcnt bookkeeping uniform
    ISSUE_BATCH(kk, cur);
    for (int i = 0; i < 4; ++i)
      for (int j = 0; j < 4; ++j)
        acc[i][j] =
            __builtin_amdgcn_mfma_f32_16x16x32_bf16(af[i], bfr[j], acc[i][j], 0, 0, 0);
  }

  // ---- fused epilogue: h = relu(acc + b1), y-partial = h * W2[e] ----
  float y0[4][4], y1[4][4];
  for (int i = 0; i < 4; ++i)
    for (int r2 = 0; r2 < 4; ++r2) y0[i][r2] = y1[i][r2] = 0.f;

  for (int j = 0; j < 4; ++j) {
    int col = n0 + wn + j * 16 + lm;
    float bias = b1[e * N_H + col];
    float2 w2 = *(const float2*)&W2[((size_t)e * N_H + col) * N_C];
    for (int i = 0; i < 4; ++i) {
      f32x4 a = acc[i][j];
      for (int r2 = 0; r2 < 4; ++r2) {
        float h = a[r2] + bias;
        h = h > 0.f ? h : 0.f;
        y0[i][r2] += h * w2.x;
        y1[i][r2] += h * w2.y;
      }
    }
  }
  for (int s = 1; s < 16; s <<= 1) {
    for (int i = 0; i < 4; ++i)
      for (int r2 = 0; r2 < 4; ++r2) {
        y0[i][r2] += __shfl_xor(y0[i][r2], s, 64);
        y1[i][r2] += __shfl_xor(y1[i][r2], s, 64);
      }
  }
  if (lm == 0) {
    const bool add_bias = (n0 == 0) && (wn == 0);
    float bb0 = add_bias ? b2[e * N_C + 0] : 0.f;
    float bb1 = add_bias ? b2[e * N_C + 1] : 0.f;
    for (int i = 0; i < 4; ++i) {
      for (int r2 = 0; r2 < 4; ++r2) {
        int mrel = wm + i * 16 + quad * 4 + r2;
        if (mrel < cnt_rel) {
          int token = sorted[off + m0 + mrel];
          atomicAdd(&out[(size_t)token * N_C + 0], y0[i][r2] + bb0);
          atomicAdd(&out[(size_t)token * N_C + 1], y1[i][r2] + bb1);
        }
      }
    }
  }
}

// ---------------- launch ----------------

extern "C" void kernel_launch(void* const* d_in, const int* in_sizes, int n_in,
                              void* d_out, int out_size, void* d_ws, size_t ws_size,
                              hipStream_t stream) {
  const float* emb = (const float*)d_in[0];
  const int* cidx = (const int*)d_in[1];
  const float* W1 = (const float*)d_in[2];
  const float* b1 = (const float*)d_in[3];
  const float* W2 = (const float*)d_in[4];
  const float* b2 = (const float*)d_in[5];
  float* out = (float*)d_out;
  const int n = in_sizes[1];

  char* ws = (char*)d_ws;
  int* counts = (int*)ws;
  int* offsets = (int*)(ws + 128);
  int* cursor = (int*)(ws + 256);
  int* numTiles = (int*)(ws + 384);
  int* tiles = (int*)(ws + 512);
  int* sorted = (int*)(ws + 2048);
  size_t sorted_bytes = ((size_t)n * 4 + 255) & ~(size_t)255;
  unsigned short* Xg = (unsigned short*)(ws + 2048 + sorted_bytes);
  int pcap = n + MT;  // zero-padded tail rows
  unsigned short* W1t = Xg + (size_t)pcap * N_D;

  // 3 dispatches, no memsets. All workspace state is rewritten every call.
  k_front<<<1, 256, 0, stream>>>(cidx, counts, offsets, cursor, tiles, numTiles, n);
  int nbsg = (n + SG_TOK - 1) / SG_TOK + 1;  // sg blocks + 1 pad/out-zero block
  k_mid<<<nbsg + W1BLKS, 256, 0, stream>>>(cidx, cursor, sorted, emb, Xg, W1, W1t,
                                           out, n, nbsg);
  k_gemm<<<dim3(NCOL, MAX_TILES), 256, 0, stream>>>(
      Xg, W1t, b1, W2, b2, sorted, counts, offsets, tiles, numTiles, out);
}